// Round 11
// baseline (235.519 us; speedup 1.0000x reference)
//
#include <hip/hip_runtime.h>
#include <hip/hip_bf16.h>
#include <math.h>

#define HEADS 16
#define KV_HEADS 8
#define DIMS 64
#define IN_DIMS 1024
#define BATCH 2
#define SEQ 2048

typedef __attribute__((ext_vector_type(8))) short short8;   // 8 bf16 (4 VGPRs)
typedef __attribute__((ext_vector_type(4))) float f32x4;    // MFMA accumulator

__device__ __forceinline__ short f2bf(float f) {
    __hip_bfloat16 h = __float2bfloat16(f);
    return *reinterpret_cast<short*>(&h);
}

#define LOG2_10000 13.287712379549449f
#define CSCALE (0.5f * 1.4426950408889634f)   // attn scale * log2(e)

// ---------------------------------------------------------------------------
// All weight prep in ONE launch (z-indexed). r9/r10-verified.
// ---------------------------------------------------------------------------
__global__ __launch_bounds__(256) void prep_weights(
    const float* __restrict__ Wq, const float* __restrict__ Wk,
    const float* __restrict__ Wv, const float* __restrict__ Wo,
    short* __restrict__ WT, short* __restrict__ WoPt)
{
    __shared__ float t[32][33];
    int z = blockIdx.z;
    int bx = blockIdx.x * 32, by = blockIdx.y * 32;
    int x = threadIdx.x & 31, y = threadIdx.x >> 5;
    if (z == 3) {
        if (by >= 512) return;
        #pragma unroll
        for (int i = 0; i < 32; i += 8) {
            int d = by + y + i;
            t[y + i][x] = Wo[(size_t)(2 * d) * 1024 + bx + x]
                        + Wo[(size_t)(2 * d + 1) * 1024 + bx + x];
        }
        __syncthreads();
        #pragma unroll
        for (int i = 0; i < 32; i += 8)
            WoPt[(size_t)(bx + y + i) * 512 + by + x] = f2bf(t[x][y + i]);
    } else {
        const float* W = (z == 0) ? Wq : ((z == 1) ? Wk : Wv);
        int N = (z == 0) ? 1024 : 512;
        if (bx >= N) return;
        short* dst = WT + ((z == 0) ? 0 : ((z == 1) ? (size_t)1024 * 1024
                                                    : (size_t)1536 * 1024));
        #pragma unroll
        for (int i = 0; i < 32; i += 8)
            t[y + i][x] = W[(size_t)(by + y + i) * N + bx + x];
        __syncthreads();
        #pragma unroll
        for (int i = 0; i < 32; i += 8)
            dst[(size_t)(bx + y + i) * 1024 + by + x] = f2bf(t[x][y + i]);
    }
}

// ---------------------------------------------------------------------------
// f32 -> bf16 cast (q). r8-verified.
// ---------------------------------------------------------------------------
__global__ __launch_bounds__(256) void cvt_f32_bf16(
    const float* __restrict__ src, short* __restrict__ dst, int n4)
{
    int i = blockIdx.x * blockDim.x + threadIdx.x;
    if (i >= n4) return;
    float4 v = ((const float4*)src)[i];
    short4 s = { f2bf(v.x), f2bf(v.y), f2bf(v.z), f2bf(v.w) };
    ((short4*)dst)[i] = s;
}

// ---------------------------------------------------------------------------
// RoPE (cos,sin) tables -- same sincosf values as r10's prep kernels, so the
// fused epilogue below is numerically identical to the verified r10 path.
// TQ[pos][i<512] for Q (dim 1024), TK[pos][i<256] for K (dim 512).
// ---------------------------------------------------------------------------
__global__ __launch_bounds__(256) void rope_tables(
    float2* __restrict__ TQ, float2* __restrict__ TK)
{
    int pos = blockIdx.y;
    int i = blockIdx.x * 256 + threadIdx.x;   // 0..767
    float sn, cs;
    if (i < 512) {
        float theta = exp2f(-(float)i * (LOG2_10000 / 512.f));
        sincosf((float)(pos + 1) * theta, &sn, &cs);
        TQ[(size_t)pos * 512 + i] = make_float2(cs, sn);
    } else {
        int k = i - 512;
        float theta = exp2f(-(float)k * (LOG2_10000 / 256.f));
        sincosf((float)(pos + 1) * theta, &sn, &cs);
        TK[(size_t)pos * 256 + k] = make_float2(cs, sn);
    }
}

// ---------------------------------------------------------------------------
// Fused QKV GEMM + table-lookup RoPE epilogue (no transcendentals, no calls
// -> no scratch spills; r9's numerics, r8's bf16 staging).
// C-tile = qb[M,1024] @ WT[2048,1024]^T, BM=BN=128, BK=64, 4 waves.
// Q cols [0,1024): rope+pair-sum+scale -> Qp; K cols [1024,1536): rope -> Kb;
// V cols [1536,2048): cvt -> Vb.  Pair partner via shfl_xor(1).
// ---------------------------------------------------------------------------
__global__ __launch_bounds__(256) void qkv_gemm(
    const short* __restrict__ qb, const short* __restrict__ WT,
    const float2* __restrict__ TQ, const float2* __restrict__ TK,
    short* __restrict__ Qp, short* __restrict__ Kb, short* __restrict__ Vb)
{
    __shared__ short As[128][72];
    __shared__ short Bs[128][72];

    int tid  = threadIdx.x;
    int lane = tid & 63, wave = tid >> 6;
    int quad = lane >> 4, ln = lane & 15;
    int wm = (wave >> 1) * 64, wn = (wave & 1) * 64;
    int row0 = blockIdx.y * 128, col0 = blockIdx.x * 128;
    const int K = 1024;

    f32x4 acc[4][4] = {};

    for (int kt = 0; kt < K; kt += 64) {
        #pragma unroll
        for (int u = 0; u < 4; ++u) {
            int idx = u * 2048 + tid * 8;
            int r  = idx >> 6;
            int kk = idx & 63;
            *(short8*)&As[r][kk] = *(const short8*)(qb + (size_t)(row0 + r) * K + kt + kk);
            *(short8*)&Bs[r][kk] = *(const short8*)(WT + (size_t)(col0 + r) * K + kt + kk);
        }
        __syncthreads();

        #pragma unroll
        for (int k0 = 0; k0 < 64; k0 += 32) {
            short8 af[4], bfr[4];
            #pragma unroll
            for (int i = 0; i < 4; ++i)
                af[i] = *(const short8*)&As[wm + 16 * i + ln][k0 + quad * 8];
            #pragma unroll
            for (int j = 0; j < 4; ++j)
                bfr[j] = *(const short8*)&Bs[wn + 16 * j + ln][k0 + quad * 8];
            #pragma unroll
            for (int i = 0; i < 4; ++i)
                #pragma unroll
                for (int j = 0; j < 4; ++j)
                    acc[i][j] = __builtin_amdgcn_mfma_f32_16x16x32_bf16(
                        af[i], bfr[j], acc[i][j], 0, 0, 0);
        }
        __syncthreads();
    }

    // ---- Region-dispatched epilogue (block-uniform; pure loads + FMA) ----
    if (col0 < 1024) {                    // Q: rope + pair-sum + scale
        #pragma unroll
        for (int j = 0; j < 4; ++j) {
            int col = col0 + wn + 16 * j + ln;
            int ii  = col >> 1;
            #pragma unroll
            for (int i = 0; i < 4; ++i)
                #pragma unroll
                for (int r = 0; r < 4; ++r) {
                    int row = row0 + wm + 16 * i + quad * 4 + r;
                    float2 t = TQ[(size_t)(row & (SEQ - 1)) * 512 + ii];
                    float x  = acc[i][j][r];
                    float xp = __shfl_xor(x, 1);
                    float val = (x * (t.x + t.y) + xp * (t.x - t.y)) * CSCALE;
                    if (!(ln & 1))
                        Qp[(size_t)row * 512 + ii] = f2bf(val);
                }
        }
    } else if (col0 < 1536) {             // K: rope
        #pragma unroll
        for (int j = 0; j < 4; ++j) {
            int kcol = col0 - 1024 + wn + 16 * j + ln;
            int ii   = kcol >> 1;
            #pragma unroll
            for (int i = 0; i < 4; ++i)
                #pragma unroll
                for (int r = 0; r < 4; ++r) {
                    int row = row0 + wm + 16 * i + quad * 4 + r;
                    float2 t = TK[(size_t)(row & (SEQ - 1)) * 256 + ii];
                    float x  = acc[i][j][r];
                    float xp = __shfl_xor(x, 1);
                    float val = (ln & 1) ? (xp * t.y + x * t.x)
                                         : (x * t.x - xp * t.y);
                    Kb[(size_t)row * 512 + kcol] = f2bf(val);
                }
        }
    } else {                              // V: plain bf16
        #pragma unroll
        for (int j = 0; j < 4; ++j) {
            int vcol = col0 - 1536 + wn + 16 * j + ln;
            #pragma unroll
            for (int i = 0; i < 4; ++i)
                #pragma unroll
                for (int r = 0; r < 4; ++r) {
                    int row = row0 + wm + 16 * i + quad * 4 + r;
                    Vb[(size_t)row * 512 + vcol] = f2bf(acc[i][j][r]);
                }
        }
    }
}

// ---------------------------------------------------------------------------
// bf16 V transpose: Vtg[b][d][key] = Vb[b*SEQ+key][d].  r8-verified.
// ---------------------------------------------------------------------------
__global__ __launch_bounds__(256) void transpose_v16(
    const short* __restrict__ Vb, short* __restrict__ Vtg)
{
    __shared__ short t[64][72];
    int d0 = blockIdx.x * 64;
    int k0 = blockIdx.y * 64;
    int b  = blockIdx.z;
    int tid = threadIdx.x;
    int rr = tid >> 3, cc = (tid & 7) * 8;
    #pragma unroll
    for (int u = 0; u < 2; ++u) {
        int key = k0 + u * 32 + rr;
        *(short8*)&t[u * 32 + rr][cc] =
            *(const short8*)(Vb + (size_t)(b * SEQ + key) * 512 + d0 + cc);
    }
    __syncthreads();
    #pragma unroll
    for (int u = 0; u < 2; ++u) {
        int d = u * 32 + rr;
        short8 v;
        #pragma unroll
        for (int s = 0; s < 8; ++s) v[s] = t[cc + s][d];
        *(short8*)(Vtg + ((size_t)b * 512 + d0 + d) * SEQ + k0 + cc) = v;
    }
}

// ---------------------------------------------------------------------------
// MFMA flash attention, S-TRANSPOSED formulation.
// QK^T computed as S^T = mfma(K-frag, Q-frag): D[m=key-local][n=q-local].
//  -> thread (quad,ln) holds p-values for q = qw+ln, keys j0*16+quad*4+r
//  -> Ps[q][key] writes are key-contiguous short4: 4 ds_write_b64/wave-iter
//     (was 16 ds_write_b16) -- stride 80 shorts = bank-uniform AND 16B-row-
//     aligned so PV's b128 A-frag reads stay single-instruction.
//  -> l accumulates in ONE scalar/thread; 2 shfls per block total.
//  -> Ps rows are wave-private: no barrier between Ps write and PV read
//     (in-wave DS ordering). 2 barriers/iter instead of 3.
// Q-frag loaded once from global (no Qs tile). LDS = Ks[64][40]+Vt[32][72]
// +Ps[64][80] = 20.0 KB.  One block = (b,h,64 queries), 256 thr, grid 1024.
// ---------------------------------------------------------------------------
__global__ __launch_bounds__(256) void flash_attn(
    const short* __restrict__ Qp, const short* __restrict__ Kb,
    const short* __restrict__ Vtg, short* __restrict__ AO32)
{
    __shared__ short Ks[64][40];
    __shared__ short Vt[32][72];
    __shared__ short Ps[64][80];

    int tid = threadIdx.x;
    int qt = blockIdx.x & 31;
    int h  = (blockIdx.x >> 5) & 15;
    int b  = blockIdx.x >> 9;

    int lane = tid & 63, wave = tid >> 6;
    int quad = lane >> 4, ln = lane & 15;
    int qw = wave * 16;

    // Loop-invariant Q fragment straight from global (A-layout for S^T's B op)
    short8 af = *(const short8*)(
        Qp + (size_t)(b * SEQ + qt * 64 + qw + ln) * 512 + h * 32 + quad * 8);

    const short* Kgb = Kb + (size_t)(b * SEQ) * 512 + 32 * h;
    const short* Vgb = Vtg + ((size_t)b * 512 + 32 * h) * SEQ;

    float lpart = 0.f;
    f32x4 Oacc[2] = {};

    for (int kt = 0; kt < SEQ; kt += 64) {
        __syncthreads();
        // Stage K: 64 keys x 32 bf16 (1 short8/thread)
        {
            int key = tid >> 2, off = (tid & 3) * 8;
            *(short8*)&Ks[key][off] =
                *(const short8*)(Kgb + (size_t)(kt + key) * 512 + off);
        }
        // Stage V: 32 dims x 64 keys (1 short8/thread)
        {
            int d = tid >> 3, koff = (tid & 7) * 8;
            *(short8*)&Vt[d][koff] =
                *(const short8*)(Vgb + (size_t)d * SEQ + kt + koff);
        }
        __syncthreads();

        // S^T per 16-key group: D[m=key=quad*4+r][n=q=ln]
        #pragma unroll
        for (int j0 = 0; j0 < 4; ++j0) {
            short8 kf = *(const short8*)&Ks[j0 * 16 + ln][quad * 8];
            f32x4 z = {};
            f32x4 st = __builtin_amdgcn_mfma_f32_16x16x32_bf16(kf, af, z, 0, 0, 0);
            float p0 = exp2f(st[0]);
            float p1 = exp2f(st[1]);
            float p2 = exp2f(st[2]);
            float p3 = exp2f(st[3]);
            lpart += (p0 + p1) + (p2 + p3);
            short4 ps = { f2bf(p0), f2bf(p1), f2bf(p2), f2bf(p3) };
            *(short4*)&Ps[qw + ln][j0 * 16 + quad * 4] = ps;
        }

        // PV: Oacc[ng] += P(16x64) @ V(64x16)  (Ps rows wave-private)
        #pragma unroll
        for (int kg = 0; kg < 2; ++kg) {
            short8 pf = *(const short8*)&Ps[qw + ln][kg * 32 + quad * 8];
            #pragma unroll
            for (int ng = 0; ng < 2; ++ng) {
                short8 vf = *(const short8*)&Vt[ng * 16 + ln][kg * 32 + quad * 8];
                Oacc[ng] = __builtin_amdgcn_mfma_f32_16x16x32_bf16(
                    pf, vf, Oacc[ng], 0, 0, 0);
            }
        }
    }

    // l: reduce over the 4 quads holding disjoint key-subsets of q = qw+ln
    lpart += __shfl_xor(lpart, 16);
    lpart += __shfl_xor(lpart, 32);

    // Epilogue: Oacc D-layout row q-local = quad*4+r needs l[qw+quad*4+r],
    // which lives at lane (quad*4+r) -- fetch via bpermute shfl.
    #pragma unroll
    for (int r = 0; r < 4; ++r) {
        float linv = 1.f / __shfl(lpart, quad * 4 + r);
        size_t row = (size_t)(b * SEQ) + qt * 64 + qw + quad * 4 + r;
        #pragma unroll
        for (int ng = 0; ng < 2; ++ng)
            AO32[row * 512 + h * 32 + ng * 16 + ln] = f2bf(Oacc[ng][r] * linv);
    }
}

// ---------------------------------------------------------------------------
// Output GEMM: out[4096][1024] = AO32[4096][512] @ WoPt[1024][512]^T.
// r9/r10-verified.
// ---------------------------------------------------------------------------
__global__ __launch_bounds__(256) void gemm_wo(
    const short* __restrict__ A, const short* __restrict__ Bt,
    float* __restrict__ C)
{
    __shared__ short As[64][72];
    __shared__ short Bs[128][72];

    int tid  = threadIdx.x;
    int lane = tid & 63, wave = tid >> 6;
    int quad = lane >> 4, ln = lane & 15;
    int wm = (wave >> 1) * 32, wn = (wave & 1) * 64;
    int row0 = blockIdx.y * 64, col0 = blockIdx.x * 128;
    const int K = 512, N = 1024;

    f32x4 acc[2][4] = {};

    for (int kt = 0; kt < K; kt += 64) {
        #pragma unroll
        for (int u = 0; u < 2; ++u) {
            int idx = u * 2048 + tid * 8;
            int r  = idx >> 6;
            int kk = idx & 63;
            *(short8*)&As[r][kk] = *(const short8*)(A + (size_t)(row0 + r) * K + kt + kk);
        }
        #pragma unroll
        for (int u = 0; u < 4; ++u) {
            int idx = u * 2048 + tid * 8;
            int r  = idx >> 6;
            int kk = idx & 63;
            *(short8*)&Bs[r][kk] = *(const short8*)(Bt + (size_t)(col0 + r) * K + kt + kk);
        }
        __syncthreads();

        #pragma unroll
        for (int k0 = 0; k0 < 64; k0 += 32) {
            short8 af[2], bfr[4];
            #pragma unroll
            for (int i = 0; i < 2; ++i)
                af[i] = *(const short8*)&As[wm + 16 * i + ln][k0 + quad * 8];
            #pragma unroll
            for (int j = 0; j < 4; ++j)
                bfr[j] = *(const short8*)&Bs[wn + 16 * j + ln][k0 + quad * 8];
            #pragma unroll
            for (int i = 0; i < 2; ++i)
                #pragma unroll
                for (int j = 0; j < 4; ++j)
                    acc[i][j] = __builtin_amdgcn_mfma_f32_16x16x32_bf16(
                        af[i], bfr[j], acc[i][j], 0, 0, 0);
        }
        __syncthreads();
    }

    #pragma unroll
    for (int i = 0; i < 2; ++i)
        #pragma unroll
        for (int j = 0; j < 4; ++j)
            #pragma unroll
            for (int r = 0; r < 4; ++r)
                C[(size_t)(row0 + wm + 16 * i + quad * 4 + r) * N
                  + col0 + wn + 16 * j + ln] = acc[i][j][r];
}

// ---------------------------------------------------------------------------
extern "C" void kernel_launch(void* const* d_in, const int* in_sizes, int n_in,
                              void* d_out, int out_size, void* d_ws, size_t ws_size,
                              hipStream_t stream)
{
    const float* q  = (const float*)d_in[0];
    const float* Wq = (const float*)d_in[1];
    const float* Wk = (const float*)d_in[2];
    const float* Wv = (const float*)d_in[3];
    const float* Wo = (const float*)d_in[4];
    float* out = (float*)d_out;

    const int M = BATCH * SEQ;          // 4096

    // ws (shorts): qb [4096][1024] 8.4MB (AO32 aliases qb; qb dead after
    // qkv_gemm) | WT 4.2 | WoPt 1.0 | Qp 4.2 | Kb 4.2 | Vb 4.2 | Vtg 4.2 |
    // TQ (float2) 8.4 | TK (float2) 4.2.  Total 43.2 MB.
    short* qb   = (short*)d_ws;
    short* WT   = qb + (size_t)M * 1024;
    short* WoPt = WT + (size_t)2048 * 1024;
    short* Qp   = WoPt + (size_t)1024 * 512;
    short* Kb   = Qp + (size_t)M * 512;
    short* Vb   = Kb + (size_t)M * 512;
    short* Vtg  = Vb + (size_t)M * 512;
    float2* TQ  = (float2*)(Vtg + (size_t)M * 512);
    float2* TK  = TQ + (size_t)SEQ * 512;
    short* AO32 = qb;   // alias

    dim3 blk(256);

    // 1) Weight prep (one launch) + rope tables + q cast
    prep_weights<<<dim3(32, 32, 4), blk, 0, stream>>>(Wq, Wk, Wv, Wo, WT, WoPt);
    rope_tables<<<dim3(3, SEQ), blk, 0, stream>>>(TQ, TK);
    cvt_f32_bf16<<<(M * 1024 / 4 + 255) / 256, blk, 0, stream>>>(q, qb, M * 1024 / 4);

    // 2) Fused QKV GEMM + table-rope epilogue -> Qp, Kb, Vb (XQKV eliminated)
    qkv_gemm<<<dim3(16, 32), blk, 0, stream>>>(qb, WT, TQ, TK, Qp, Kb, Vb);

    // 3) V transpose (bf16)
    transpose_v16<<<dim3(8, 32, BATCH), blk, 0, stream>>>(Vb, Vtg);

    // 4) Flash attention (S^T formulation) -> AO32 (aliases qb)
    flash_attn<<<BATCH * HEADS * (SEQ / 64), blk, 0, stream>>>(Qp, Kb, Vtg, AO32);

    // 5) Output GEMM -> f32 out
    gemm_wo<<<dim3(8, 64), blk, 0, stream>>>(AO32, WoPt, out);
}